// Round 4
// baseline (663.448 us; speedup 1.0000x reference)
//
#include <hip/hip_runtime.h>
#include <cstdint>
#include <cstddef>

// Problem constants (fixed by reference)
#define BATCH 32
#define SEQ   2048
#define DIM   1024      // ENC_D = DEC_D = ATTN_D = OUT_D = 1024
#define MROWS (BATCH*SEQ)   // 65536

typedef __attribute__((ext_vector_type(4))) float  floatx4;
typedef __attribute__((ext_vector_type(8))) short  short8;

// fp32 -> bf16 round-to-nearest-even (used in prep where cost doesn't matter)
__device__ __forceinline__ unsigned short f2bf(float f) {
  unsigned int u = __float_as_uint(f);
  u += 0x7fffu + ((u >> 16) & 1u);
  return (unsigned short)(u >> 16);
}

// pack two fp32 -> two bf16 in one dword; round-half-up (u+0x8000) + v_perm.
// Differs from RTNE only on exact ties (prob ~2^-16, same magnitude) -> 3 VALU ops.
__device__ __forceinline__ unsigned int pack2(float lo, float hi) {
  unsigned int a = __float_as_uint(lo) + 0x8000u;
  unsigned int b = __float_as_uint(hi) + 0x8000u;
  // dst bytes: {b[3], b[2], a[3], a[2]} => (hi16(b) << 16) | hi16(a)
  return __builtin_amdgcn_perm(b, a, 0x07060302u);
}

// async global->LDS, 16B per lane; LDS dest = wave-uniform base + lane*16
__device__ __forceinline__ void async16(const void* g, void* l) {
  __builtin_amdgcn_global_load_lds(
      (const __attribute__((address_space(1))) unsigned int*)g,
      (__attribute__((address_space(3))) unsigned int*)l, 16, 0, 0);
}

__device__ __forceinline__ float fast_tanh(float x) {
  float e = __expf(2.0f * x);
  return 1.0f - 2.0f * __builtin_amdgcn_rcpf(1.0f + e);
}

// ---------------------------------------------------------------------------
// k_prep: fused preprocessing (independent jobs, one dispatch):
//   blocks [0,1024)    : Wt[n][k] = bf16(W_enc[k][n])
//   blocks [1024,2048) : dech[b][a] += dec[b]@W_dec (split-K x8) + biases
//                        (dech pre-zeroed by the memset before this kernel)
//   blocks [2048,2052) : zero out_ctx (accumulated later by k_out)
// ---------------------------------------------------------------------------
__global__ void k_prep(const float* __restrict__ W_enc, unsigned short* __restrict__ Wt,
                       const float* __restrict__ dec, const float* __restrict__ W_dec,
                       const float* __restrict__ b_dec, const float* __restrict__ b_enc,
                       float* __restrict__ dech, float* __restrict__ out_ctx) {
  int id = blockIdx.x;
  int tid = threadIdx.x;
  if (id < 1024) {
    // ---- transpose+convert W_enc ----
    int n0 = (id & 31) * 32, k0 = (id >> 5) * 32;
    __shared__ float tile[32][33];
    int tx = tid & 31, ty = tid >> 5;     // 32 x 8
#pragma unroll
    for (int i = 0; i < 4; ++i) {
      int y = ty + i * 8;
      tile[y][tx] = W_enc[(size_t)(k0 + y) * DIM + n0 + tx];
    }
    __syncthreads();
#pragma unroll
    for (int i = 0; i < 4; ++i) {
      int y = ty + i * 8;
      Wt[(size_t)(n0 + y) * DIM + k0 + tx] = f2bf(tile[tx][y]);
    }
  } else if (id < 2048) {
    // ---- dec_h GEMV, split-K x8 ----
    int t = id - 1024;
    int x = t & 3, b = (t >> 2) & 31, z = t >> 7;
    int a = x * 256 + tid;
    float acc = (z == 0) ? (b_dec[a] + b_enc[a]) : 0.0f;
    const float* dr = dec + (size_t)b * DIM + z * 128;
    const float* wc = W_dec + (size_t)z * 128 * DIM + a;
#pragma unroll 8
    for (int e = 0; e < 128; ++e)
      acc = fmaf(dr[e], wc[(size_t)e * DIM], acc);
    atomicAdd(&dech[(size_t)b * DIM + a], acc);
  } else {
    // ---- zero out_ctx: 4 blocks x 256 threads x 8 float4 = 32768 floats ----
    int t = id - 2048;
    float4* p = (float4*)out_ctx;
#pragma unroll
    for (int i = 0; i < 8; ++i)
      p[(t * 256 + tid) * 8 + i] = make_float4(0.f, 0.f, 0.f, 0.f);
  }
}

// ---------------------------------------------------------------------------
// GEMM + tanh-dot epilogue. 128x128 tile, BK=64 (16 K-iters), 16x16x32 bf16
// MFMA, 4 waves (2x2 of 64x64), fp32 A converted in-staging.
//
// LDS layout (both sA and sB): 128 rows x 8 chunks of 16B (8 bf16).
//   physical chunk = row*8 + (q ^ (row & 7))   [XOR bank swizzle]
// - staging ds_write_b128: lanes hit phys%8 = lane%8 -> all 32 banks, free
// - fragment ds_read_b128 (fixed q, 16 rows): row&7 covers 0..7 twice ->
//   2 lanes/bank-group = 2-way = free (m136)
// B is staged via global_load_lds (lane computes swizzled source address;
// the q-permutation stays inside a 64B row segment -> coalescing preserved).
// ---------------------------------------------------------------------------
__global__ void __launch_bounds__(256, 2) k_gemm(
    const float* __restrict__ A,            // enc_states [65536,1024] fp32
    const unsigned short* __restrict__ Wt,  // [1024 n][1024 k] bf16
    const float* __restrict__ dech,         // [32,1024]
    const float* __restrict__ w_attn,       // [1024]
    const int* __restrict__ enc_len,        // [32]
    float* __restrict__ score)              // [65536], pre-zeroed
{
  int linear = blockIdx.x;          // 0..4095
  int xcd = linear & 7;
  int j   = linear >> 3;
  int rb  = xcd * 64 + (j >> 3);    // row block 0..511 (8 col-blocks adjacent per XCD)
  int nb  = j & 7;                  // col block 0..7

  int bb  = rb >> 4;
  int len = enc_len[bb];
  if (((rb & 15) * 128) >= len) return;   // fully masked tile

  __shared__ __align__(16) unsigned short sA[128 * 64];  // 16 KB
  __shared__ __align__(16) unsigned short sB[128 * 64];  // 16 KB

  int tid  = threadIdx.x;
  int w    = tid >> 6, lane = tid & 63;
  int wm   = (w >> 1) * 64, wn = (w & 1) * 64;
  int li   = lane & 15, g = lane >> 4;

  const float*          Ab = A  + (size_t)rb * 128 * DIM;
  const unsigned short* Bb = Wt + (size_t)nb * 128 * DIM;

  floatx4 acc[4][4] = {};

  for (int kb = 0; kb < 16; ++kb) {   // 1024 / 64
    __syncthreads();
    // --- stage B: 1024 chunks via async16, 16 wave-uniform segments ---
#pragma unroll
    for (int i = 0; i < 4; ++i) {
      int seg = i * 4 + w;
      int p   = seg * 64 + lane;
      int row = p >> 3, qp = p & 7;
      int ql  = qp ^ (row & 7);
      async16(Bb + (size_t)row * DIM + kb * 64 + ql * 8, (char*)sB + seg * 1024);
    }
    // --- stage A: fp32 load -> half-up bf16 pack -> ds_write_b128, 4 chunks/thread ---
#pragma unroll
    for (int i = 0; i < 4; ++i) {
      int p   = tid + i * 256;
      int row = p >> 3, qp = p & 7;
      int ql  = qp ^ (row & 7);
      const float* src = Ab + (size_t)row * DIM + kb * 64 + ql * 8;
      float4 v0 = *(const float4*)src;
      float4 v1 = *(const float4*)(src + 4);
      int4 pk;
      pk.x = (int)pack2(v0.x, v0.y);
      pk.y = (int)pack2(v0.z, v0.w);
      pk.z = (int)pack2(v1.x, v1.y);
      pk.w = (int)pack2(v1.z, v1.w);
      *(int4*)&sA[(size_t)p * 8] = pk;
    }
    __syncthreads();

    // --- two K=32 sub-phases, 16 MFMA each ---
#pragma unroll
    for (int h = 0; h < 2; ++h) {
      short8 af[4], bfr[4];
#pragma unroll
      for (int t = 0; t < 4; ++t) {
        int row = wm + t * 16 + li;
        int ca  = row * 8 + ((h * 4 + g) ^ (row & 7));
        af[t]   = *(const short8*)&sA[(size_t)ca * 8];
        int n   = wn + t * 16 + li;
        int cb  = n * 8 + ((h * 4 + g) ^ (n & 7));
        bfr[t]  = *(const short8*)&sB[(size_t)cb * 8];
      }
#pragma unroll
      for (int tm = 0; tm < 4; ++tm)
#pragma unroll
        for (int tn = 0; tn < 4; ++tn)
          acc[tm][tn] = __builtin_amdgcn_mfma_f32_16x16x32_bf16(af[tm], bfr[tn], acc[tm][tn], 0, 0, 0);
    }
  }

  // --- epilogue: C/D layout col=lane&15, row=(lane>>4)*4+reg  [m89] ---
  float dh[4], wa[4];
#pragma unroll
  for (int tn = 0; tn < 4; ++tn) {
    int n = nb * 128 + wn + tn * 16 + li;
    dh[tn] = dech[(size_t)bb * DIM + n];
    wa[tn] = w_attn[n];
  }
#pragma unroll
  for (int tm = 0; tm < 4; ++tm) {
    int mrow = rb * 128 + wm + tm * 16 + g * 4;
#pragma unroll
    for (int r = 0; r < 4; ++r) {
      float v = 0.0f;
#pragma unroll
      for (int tn = 0; tn < 4; ++tn)
        v = fmaf(wa[tn], fast_tanh(acc[tm][tn][r] + dh[tn]), v);
      v += __shfl_xor(v, 1);
      v += __shfl_xor(v, 2);
      v += __shfl_xor(v, 4);
      v += __shfl_xor(v, 8);
      if (li == 0) atomicAdd(&score[mrow + r], v);
    }
  }
}

// ---------------------------------------------------------------------------
// masked softmax per batch row. SCALING == 1.0 (folded out).
// ---------------------------------------------------------------------------
__global__ void k_softmax(const float* __restrict__ score, const int* __restrict__ enc_len,
                          float* __restrict__ attn) {
  int b = blockIdx.x, tid = threadIdx.x;
  int len = enc_len[b];
  __shared__ float red[256];
  float v[8];
  float m = -1e30f;
#pragma unroll
  for (int i = 0; i < 8; ++i) {
    int s = tid + i * 256;
    v[i] = score[(size_t)b * SEQ + s];
    if (s < len) m = fmaxf(m, v[i]);
  }
  red[tid] = m; __syncthreads();
  for (int st = 128; st > 0; st >>= 1) {
    if (tid < st) red[tid] = fmaxf(red[tid], red[tid + st]);
    __syncthreads();
  }
  float mx = red[0]; __syncthreads();
  float sum = 0.0f;
#pragma unroll
  for (int i = 0; i < 8; ++i) {
    int s = tid + i * 256;
    float e = (s < len) ? __expf(v[i] - mx) : 0.0f;
    v[i] = e; sum += e;
  }
  red[tid] = sum; __syncthreads();
  for (int st = 128; st > 0; st >>= 1) {
    if (tid < st) red[tid] += red[tid + st];
    __syncthreads();
  }
  float inv = 1.0f / red[0];
#pragma unroll
  for (int i = 0; i < 8; ++i)
    attn[(size_t)b * SEQ + tid + i * 256] = v[i] * inv;
}

// ---------------------------------------------------------------------------
// ctx[b][e] += sum_s attn[b][s] * enc[b][s][e]   (memory-bound streaming)
// ---------------------------------------------------------------------------
__global__ void k_context(const float* __restrict__ enc, const float* __restrict__ attn,
                          const int* __restrict__ enc_len, float* __restrict__ ctx) {
  int b = blockIdx.y, sc = blockIdx.x;
  int len = enc_len[b];
  int s0 = sc * 64;
  if (s0 >= len) return;
  int cnt = min(64, len - s0);
  int tid = threadIdx.x;
  const float* base = enc + ((size_t)b * SEQ + s0) * DIM + tid * 4;
  const float* ap   = attn + (size_t)b * SEQ + s0;
  float a0 = 0.f, a1 = 0.f, a2 = 0.f, a3 = 0.f;
  for (int i = 0; i < cnt; ++i) {
    float a = ap[i];
    float4 x = *(const float4*)(base + (size_t)i * DIM);
    a0 = fmaf(a, x.x, a0); a1 = fmaf(a, x.y, a1);
    a2 = fmaf(a, x.z, a2); a3 = fmaf(a, x.w, a3);
  }
  float* c = ctx + (size_t)b * DIM + tid * 4;
  atomicAdd(c + 0, a0); atomicAdd(c + 1, a1);
  atomicAdd(c + 2, a2); atomicAdd(c + 3, a3);
}

// ---------------------------------------------------------------------------
// out[b][o] += ctx[b, z-chunk] @ W_out[z-chunk, o]  (split-K x8)
// ---------------------------------------------------------------------------
__global__ void k_out(const float* __restrict__ ctx, const float* __restrict__ W_out,
                      const float* __restrict__ b_out, float* __restrict__ out) {
  int b = blockIdx.y, z = blockIdx.z;
  int o = blockIdx.x * 256 + threadIdx.x;
  float acc = (z == 0) ? b_out[o] : 0.0f;
  const float* cr = ctx + (size_t)b * DIM + z * 128;
  const float* wc = W_out + (size_t)z * 128 * DIM + o;
#pragma unroll 8
  for (int e = 0; e < 128; ++e)
    acc = fmaf(cr[e], wc[(size_t)e * DIM], acc);
  atomicAdd(&out[(size_t)b * DIM + o], acc);
}

// ---------------------------------------------------------------------------
extern "C" void kernel_launch(void* const* d_in, const int* in_sizes, int n_in,
                              void* d_out, int out_size, void* d_ws, size_t ws_size,
                              hipStream_t stream) {
  (void)in_sizes; (void)n_in; (void)out_size; (void)ws_size;
  const float* enc_states = (const float*)d_in[0];   // [32,2048,1024]
  const float* dec_states = (const float*)d_in[1];   // [32,1024]
  const float* W_enc      = (const float*)d_in[2];   // [1024,1024]
  const float* b_enc      = (const float*)d_in[3];   // [1024]
  const float* W_dec      = (const float*)d_in[4];   // [1024,1024]
  const float* b_dec      = (const float*)d_in[5];   // [1024]
  const float* w_attn     = (const float*)d_in[6];   // [1024]
  const float* W_out      = (const float*)d_in[7];   // [1024,1024]
  const float* b_out      = (const float*)d_in[8];   // [1024]
  const int*   enc_len    = (const int*)  d_in[9];   // [32]

  float* out_ctx  = (float*)d_out;                   // [32,1024]
  float* out_attn = (float*)d_out + BATCH * DIM;     // [32,2048]

  // workspace layout (2.5 MB):
  //   Wt    @ 0        : 2 MB   (bf16 W_enc^T)
  //   score @ 2 MB     : 256 KB (zeroed)
  //   ctx   @ 2.25 MB  : 128 KB (zeroed)
  //   dech  @ 2.375 MB : 128 KB (zeroed)
  char* ws = (char*)d_ws;
  unsigned short* Wt  = (unsigned short*)ws;
  float* score = (float*)(ws + (2u << 20));
  float* ctx   = (float*)(ws + (2u << 20) + 262144);
  float* dech  = (float*)(ws + (2u << 20) + 262144 + 131072);

  // zero score + ctx + dech (contiguous, all atomically accumulated)
  hipMemsetAsync(ws + (2u << 20), 0, 524288, stream);

  k_prep<<<2052, 256, 0, stream>>>(W_enc, Wt, dec_states, W_dec, b_dec, b_enc,
                                   dech, out_ctx);
  k_gemm<<<4096, 256, 0, stream>>>(enc_states, Wt, dech, w_attn, enc_len, score);
  k_softmax<<<BATCH, 256, 0, stream>>>(score, enc_len, out_attn);
  k_context<<<dim3(32, BATCH), 256, 0, stream>>>(enc_states, out_attn, enc_len, ctx);
  k_out<<<dim3(4, BATCH, 8), 256, 0, stream>>>(ctx, W_out, b_out, out_ctx);
}